// Round 1
// baseline (624.906 us; speedup 1.0000x reference)
//
#include <hip/hip_runtime.h>
#include <stdint.h>

typedef float f32x4v __attribute__((ext_vector_type(4)));
typedef short short8v __attribute__((ext_vector_type(8)));

__device__ __forceinline__ float bf2f(unsigned short u) {
  union { uint32_t i; float f; } v; v.i = ((uint32_t)u) << 16; return v.f;
}
__device__ __forceinline__ unsigned short f2bf(float f) {
  union { float f; uint32_t i; } v; v.f = f;
  uint32_t x = v.i;
  uint32_t r = (x + 0x7FFFu + ((x >> 16) & 1u)) >> 16;
  return (unsigned short)r;
}

// ---------------- prep: transposed bf16 weights ----------------
// W1fT[n][k], k<256 -> W1[9+k][n] (feature rows), 256<=k<265 -> W1[k-256][n] (geo rows), else 0
// W2T[n][k] = W2[k][n]
__global__ void prep_weights(const float* __restrict__ W1, const float* __restrict__ W2,
                             unsigned short* __restrict__ W1fT, unsigned short* __restrict__ W2T) {
  int i = blockIdx.x * blockDim.x + threadIdx.x;
  if (i < 256 * 288) {
    int n = i / 288, k = i % 288;
    float v = 0.f;
    if (k < 256) v = W1[(9 + k) * 256 + n];
    else if (k < 265) v = W1[(k - 256) * 256 + n];
    W1fT[i] = f2bf(v);
  }
  if (i < 256 * 256) {
    int n = i >> 8, k = i & 255;
    W2T[i] = f2bf(W2[k * 256 + n]);
  }
}

// ---------------- per-triangle geometry ----------------
// geo12[t][0..2]=t_min, [3..5]=t_max, [6..8]=barycenter, [9..11]=0 (pad)
__global__ void geo_kernel(const float* __restrict__ points, const int* __restrict__ tri,
                           float* __restrict__ geo12, int T) {
  int t = blockIdx.x * blockDim.x + threadIdx.x;
  if (t >= T) return;
  int i0 = tri[3 * t], i1 = tri[3 * t + 1], i2 = tri[3 * t + 2];
  float g[12];
#pragma unroll
  for (int c = 0; c < 3; ++c) {
    float p0 = points[i0 * 3 + c], p1 = points[i1 * 3 + c], p2 = points[i2 * 3 + c];
    float e0 = p0 - p1, e1 = p0 - p2, e2 = p1 - p2;
    float mx = fmaxf(e0, fmaxf(e1, e2));
    float mn = fminf(e0, fminf(e1, e2));
    float bc = (p0 + p1 + p2) * (1.0f / 3.0f);
    g[c] = mn; g[3 + c] = mx; g[6 + c] = bc;
  }
  g[9] = 0.f; g[10] = 0.f; g[11] = 0.f;
  float4* o = (float4*)(geo12 + (size_t)t * 12);
  o[0] = make_float4(g[0], g[1], g[2], g[3]);
  o[1] = make_float4(g[4], g[5], g[6], g[7]);
  o[2] = make_float4(g[8], g[9], g[10], g[11]);
}

// ---------------- CSR build ----------------
__global__ void count_kernel(const int* __restrict__ te, int* __restrict__ count, int E) {
  int e = blockIdx.x * blockDim.x + threadIdx.x;
  if (e < E) atomicAdd(&count[te[e]], 1);
}

// single-block scan: offsets[0..T] (exclusive on [t], total at [T]); cursor = exclusive copy
__global__ void scan_kernel(const int* __restrict__ count, int* __restrict__ offsets,
                            int* __restrict__ cursor, int T) {
  __shared__ int wsum[16];
  __shared__ int sbase;
  int tid = threadIdx.x;
  int wave = tid >> 6, lane = tid & 63;
  if (tid == 0) { sbase = 0; offsets[0] = 0; }
  __syncthreads();
  for (int chunk = 0; chunk < T; chunk += 4096) {
    int idx0 = chunk + tid * 4;
    int c0 = 0, c1 = 0, c2 = 0, c3 = 0;
    if (idx0 + 3 < T) {
      int4 v = *(const int4*)(count + idx0);
      c0 = v.x; c1 = v.y; c2 = v.z; c3 = v.w;
    } else {
      if (idx0 < T) c0 = count[idx0];
      if (idx0 + 1 < T) c1 = count[idx0 + 1];
      if (idx0 + 2 < T) c2 = count[idx0 + 2];
    }
    int s = c0 + c1 + c2 + c3;
    int incl = s;
#pragma unroll
    for (int off = 1; off < 64; off <<= 1) {
      int n = __shfl_up(incl, off);
      if (lane >= off) incl += n;
    }
    if (lane == 63) wsum[wave] = incl;
    __syncthreads();
    if (tid == 0) {
      int run = sbase;
#pragma unroll
      for (int w = 0; w < 16; ++w) { int tw = wsum[w]; wsum[w] = run; run += tw; }
      sbase = run;
    }
    __syncthreads();
    int base = wsum[wave] + (incl - s);
    int r = base;
    if (idx0 < T)     { cursor[idx0] = r;     r += c0; offsets[idx0 + 1] = r; }
    if (idx0 + 1 < T) { cursor[idx0 + 1] = r; r += c1; offsets[idx0 + 2] = r; }
    if (idx0 + 2 < T) { cursor[idx0 + 2] = r; r += c2; offsets[idx0 + 3] = r; }
    if (idx0 + 3 < T) { cursor[idx0 + 3] = r; r += c3; offsets[idx0 + 4] = r; }
    __syncthreads();
  }
}

__global__ void fill_kernel(const int* __restrict__ te, int* __restrict__ cursor,
                            int* __restrict__ tgt_list, int E) {
  int e = blockIdx.x * blockDim.x + threadIdx.x;
  if (e < E) {
    int s = te[e];
    int pos = atomicAdd(&cursor[s], 1);
    tgt_list[pos] = te[E + e];  // store tgt triangle directly (kills one indirection)
  }
}

// ---------------- U = [x | geo] @ W1 (bf16 MFMA GEMM, K=288) ----------------
__launch_bounds__(256)
__global__ void ugemm_kernel(const float* __restrict__ x, const float* __restrict__ geo12,
                             const unsigned short* __restrict__ W1fT,
                             unsigned short* __restrict__ U, int T) {
  __shared__ alignas(16) unsigned short Al[64][40];  // pad 32->40 vs bank conflicts
  __shared__ alignas(16) unsigned short Bl[64][40];
  int m0 = blockIdx.x * 64, n0 = blockIdx.y * 64;
  int tid = threadIdx.x;
  int wid = tid >> 6, lane = tid & 63;
  int wm = wid >> 1, wn = wid & 1;
  int srow = tid >> 2, cq = tid & 3;  // staging: 4 threads/row, 8 cols each
  int l15 = lane & 15, lhi = lane >> 4;
  f32x4v acc[2][2] = {};
  for (int kk = 0; kk < 9; ++kk) {
    int k0 = kk * 32;
    // ---- stage A tile [64 rows][32 k] from x (f32 -> bf16) / geo for the last step
    int t = m0 + srow;
    float f[8];
    if (kk < 8) {
      const float* sp = x + (size_t)t * 256 + k0 + cq * 8;
      float4 a = *(const float4*)sp;
      float4 b = *(const float4*)(sp + 4);
      f[0] = a.x; f[1] = a.y; f[2] = a.z; f[3] = a.w;
      f[4] = b.x; f[5] = b.y; f[6] = b.z; f[7] = b.w;
    } else {
      if (cq == 0) {
        float4 a = *(const float4*)(geo12 + (size_t)t * 12);
        float4 b = *(const float4*)(geo12 + (size_t)t * 12 + 4);
        f[0] = a.x; f[1] = a.y; f[2] = a.z; f[3] = a.w;
        f[4] = b.x; f[5] = b.y; f[6] = b.z; f[7] = b.w;
      } else if (cq == 1) {
        float4 a = *(const float4*)(geo12 + (size_t)t * 12 + 8);  // [g8,0,0,0]
        f[0] = a.x; f[1] = a.y; f[2] = a.z; f[3] = a.w;
        f[4] = 0.f; f[5] = 0.f; f[6] = 0.f; f[7] = 0.f;
      } else {
        f[0] = f[1] = f[2] = f[3] = f[4] = f[5] = f[6] = f[7] = 0.f;
      }
    }
    short8v av;
#pragma unroll
    for (int j = 0; j < 8; ++j) av[j] = (short)f2bf(f[j]);
    *(short8v*)(&Al[srow][cq * 8]) = av;
    // ---- stage B tile [64 n-rows][32 k] from W1fT (already bf16, row-major [n][288])
    short8v bv = *(const short8v*)(W1fT + (size_t)(n0 + srow) * 288 + k0 + cq * 8);
    *(short8v*)(&Bl[srow][cq * 8]) = bv;
    __syncthreads();
    // ---- MFMA: A-frag m=l15, k=8*lhi+i contiguous; B-frag n=l15, same k
    short8v a0 = *(const short8v*)(&Al[wm * 32 + l15][8 * lhi]);
    short8v a1 = *(const short8v*)(&Al[wm * 32 + 16 + l15][8 * lhi]);
    short8v b0 = *(const short8v*)(&Bl[wn * 32 + l15][8 * lhi]);
    short8v b1f = *(const short8v*)(&Bl[wn * 32 + 16 + l15][8 * lhi]);
    acc[0][0] = __builtin_amdgcn_mfma_f32_16x16x32_bf16(a0, b0, acc[0][0], 0, 0, 0);
    acc[0][1] = __builtin_amdgcn_mfma_f32_16x16x32_bf16(a0, b1f, acc[0][1], 0, 0, 0);
    acc[1][0] = __builtin_amdgcn_mfma_f32_16x16x32_bf16(a1, b0, acc[1][0], 0, 0, 0);
    acc[1][1] = __builtin_amdgcn_mfma_f32_16x16x32_bf16(a1, b1f, acc[1][1], 0, 0, 0);
    __syncthreads();
  }
  // epilogue: C/D layout col=l15, row=4*lhi+reg
#pragma unroll
  for (int mi = 0; mi < 2; ++mi)
#pragma unroll
    for (int ni = 0; ni < 2; ++ni)
#pragma unroll
      for (int i = 0; i < 4; ++i) {
        int m = wm * 32 + mi * 16 + 4 * lhi + i;
        int n = n0 + wn * 32 + ni * 16 + l15;
        U[(size_t)(m0 + m) * 256 + n] = f2bf(acc[mi][ni][i]);
      }
}

// ---------------- fused edge-gather + @W2 GEMM ----------------
// block = 32 triangles; phase 1: sum_h[32][256] = sum over CSR edges of relu(U[t]-U[tgt]+b1)
// phase 2: out[32x256] = sum_h @ W2 + count*b2 via MFMA (W2T read straight from L2)
__launch_bounds__(256)
__global__ void fused_kernel(const unsigned short* __restrict__ U,
                             const unsigned short* __restrict__ W2T,
                             const int* __restrict__ offsets,
                             const int* __restrict__ count,
                             const int* __restrict__ tgt_list,
                             const float* __restrict__ b1,
                             const float* __restrict__ b2,
                             float* __restrict__ out, int T) {
  __shared__ alignas(16) unsigned short hl[32][264];  // pad 256->264
  int t0 = blockIdx.x * 32;
  int tid = threadIdx.x, wid = tid >> 6, lane = tid & 63;
  int cb = lane * 4;  // this lane's 4 columns
  float4 b1v = *(const float4*)(b1 + cb);
  for (int r8 = 0; r8 < 8; ++r8) {
    int r = wid * 8 + r8;
    int t = t0 + r;
    int beg = offsets[t], end = offsets[t + 1];
    ushort4 us = *(const ushort4*)(U + (size_t)t * 256 + cb);
    float u0 = bf2f(us.x), u1 = bf2f(us.y), u2 = bf2f(us.z), u3 = bf2f(us.w);
    float s0 = 0.f, s1 = 0.f, s2 = 0.f, s3 = 0.f;
    for (int ei = beg; ei < end; ++ei) {
      int tg = tgt_list[ei];
      ushort4 ut = *(const ushort4*)(U + (size_t)tg * 256 + cb);
      float h0 = u0 - bf2f(ut.x) + b1v.x; s0 += fmaxf(h0, 0.f);
      float h1 = u1 - bf2f(ut.y) + b1v.y; s1 += fmaxf(h1, 0.f);
      float h2 = u2 - bf2f(ut.z) + b1v.z; s2 += fmaxf(h2, 0.f);
      float h3 = u3 - bf2f(ut.w) + b1v.w; s3 += fmaxf(h3, 0.f);
    }
    ushort4 hv;
    hv.x = f2bf(s0); hv.y = f2bf(s1); hv.z = f2bf(s2); hv.w = f2bf(s3);
    *(ushort4*)(&hl[r][cb]) = hv;
  }
  __syncthreads();
  f32x4v acc[2][4] = {};
  int l15 = lane & 15, lhi = lane >> 4;
  int nbase = wid * 64;  // each wave owns 64 output columns
  for (int kk = 0; kk < 8; ++kk) {
    int k0 = kk * 32;
    short8v a0 = *(const short8v*)(&hl[l15][k0 + 8 * lhi]);
    short8v a1 = *(const short8v*)(&hl[16 + l15][k0 + 8 * lhi]);
#pragma unroll
    for (int nf = 0; nf < 4; ++nf) {
      short8v b = *(const short8v*)(W2T + (size_t)(nbase + nf * 16 + l15) * 256 + k0 + 8 * lhi);
      acc[0][nf] = __builtin_amdgcn_mfma_f32_16x16x32_bf16(a0, b, acc[0][nf], 0, 0, 0);
      acc[1][nf] = __builtin_amdgcn_mfma_f32_16x16x32_bf16(a1, b, acc[1][nf], 0, 0, 0);
    }
  }
#pragma unroll
  for (int mi = 0; mi < 2; ++mi) {
#pragma unroll
    for (int i = 0; i < 4; ++i) {
      int m = mi * 16 + 4 * lhi + i;
      int t = t0 + m;
      float cnt = (float)count[t];
#pragma unroll
      for (int nf = 0; nf < 4; ++nf) {
        int n = nbase + nf * 16 + l15;
        out[(size_t)t * 256 + n] = acc[mi][nf][i] + cnt * b2[n];
      }
    }
  }
}

extern "C" void kernel_launch(void* const* d_in, const int* in_sizes, int n_in,
                              void* d_out, int out_size, void* d_ws, size_t ws_size,
                              hipStream_t stream) {
  const float* x = (const float*)d_in[0];
  const float* points = (const float*)d_in[1];
  const int* triangles = (const int*)d_in[2];
  const int* te = (const int*)d_in[3];
  const float* W1 = (const float*)d_in[4];
  const float* b1 = (const float*)d_in[5];
  const float* W2 = (const float*)d_in[6];
  const float* b2 = (const float*)d_in[7];
  float* out = (float*)d_out;
  int T = in_sizes[0] / 256;
  int E = in_sizes[3] / 2;

  char* ws = (char*)d_ws;
  size_t off = 0;
  auto alloc = [&](size_t bytes) {
    void* p = ws + off;
    off = (off + bytes + 255) & ~(size_t)255;
    return p;
  };
  unsigned short* U     = (unsigned short*)alloc((size_t)T * 256 * 2);
  float*          geo12 = (float*)alloc((size_t)T * 12 * 4);
  unsigned short* W1fT  = (unsigned short*)alloc((size_t)256 * 288 * 2);
  unsigned short* W2T   = (unsigned short*)alloc((size_t)256 * 256 * 2);
  int* count   = (int*)alloc((size_t)T * 4);
  int* offsets = (int*)alloc((size_t)(T + 1) * 4);
  int* cursor  = (int*)alloc((size_t)T * 4);
  int* tgtl    = (int*)alloc((size_t)E * 4);
  if (off > ws_size) return;  // workspace too small -> fail loudly (wrong output)

  hipMemsetAsync(count, 0, (size_t)T * 4, stream);
  prep_weights<<<288, 256, 0, stream>>>(W1, W2, W1fT, W2T);
  geo_kernel<<<(T + 255) / 256, 256, 0, stream>>>(points, triangles, geo12, T);
  count_kernel<<<(E + 255) / 256, 256, 0, stream>>>(te, count, E);
  scan_kernel<<<1, 1024, 0, stream>>>(count, offsets, cursor, T);
  fill_kernel<<<(E + 255) / 256, 256, 0, stream>>>(te, cursor, tgtl, E);
  ugemm_kernel<<<dim3((T + 63) / 64, 4), 256, 0, stream>>>(x, geo12, W1fT, U, T);
  fused_kernel<<<(T + 31) / 32, 256, 0, stream>>>(U, W2T, offsets, count, tgtl, b1, b2, out, T);
}

// Round 2
// 361.706 us; speedup vs baseline: 1.7277x; 1.7277x over previous
//
#include <hip/hip_runtime.h>
#include <stdint.h>

typedef float f32x4v __attribute__((ext_vector_type(4)));
typedef short short8v __attribute__((ext_vector_type(8)));

__device__ __forceinline__ float bf2f(unsigned short u) {
  union { uint32_t i; float f; } v; v.i = ((uint32_t)u) << 16; return v.f;
}
__device__ __forceinline__ unsigned short f2bf(float f) {
  union { float f; uint32_t i; } v; v.f = f;
  uint32_t x = v.i;
  uint32_t r = (x + 0x7FFFu + ((x >> 16) & 1u)) >> 16;
  return (unsigned short)r;
}

// ---------------- prep: transposed bf16 weights ----------------
__global__ void prep_weights(const float* __restrict__ W1, const float* __restrict__ W2,
                             unsigned short* __restrict__ W1fT, unsigned short* __restrict__ W2T) {
  int i = blockIdx.x * blockDim.x + threadIdx.x;
  if (i < 256 * 288) {
    int n = i / 288, k = i % 288;
    float v = 0.f;
    if (k < 256) v = W1[(9 + k) * 256 + n];
    else if (k < 265) v = W1[(k - 256) * 256 + n];
    W1fT[i] = f2bf(v);
  }
  if (i < 256 * 256) {
    int n = i >> 8, k = i & 255;
    W2T[i] = f2bf(W2[k * 256 + n]);
  }
}

// ---------------- per-triangle geometry ----------------
__global__ void geo_kernel(const float* __restrict__ points, const int* __restrict__ tri,
                           float* __restrict__ geo12, int T) {
  int t = blockIdx.x * blockDim.x + threadIdx.x;
  if (t >= T) return;
  int i0 = tri[3 * t], i1 = tri[3 * t + 1], i2 = tri[3 * t + 2];
  float g[12];
#pragma unroll
  for (int c = 0; c < 3; ++c) {
    float p0 = points[i0 * 3 + c], p1 = points[i1 * 3 + c], p2 = points[i2 * 3 + c];
    float e0 = p0 - p1, e1 = p0 - p2, e2 = p1 - p2;
    float mx = fmaxf(e0, fmaxf(e1, e2));
    float mn = fminf(e0, fminf(e1, e2));
    float bc = (p0 + p1 + p2) * (1.0f / 3.0f);
    g[c] = mn; g[3 + c] = mx; g[6 + c] = bc;
  }
  g[9] = 0.f; g[10] = 0.f; g[11] = 0.f;
  float4* o = (float4*)(geo12 + (size_t)t * 12);
  o[0] = make_float4(g[0], g[1], g[2], g[3]);
  o[1] = make_float4(g[4], g[5], g[6], g[7]);
  o[2] = make_float4(g[8], g[9], g[10], g[11]);
}

// ---------------- CSR build ----------------
__global__ void count_kernel(const int* __restrict__ te, int* __restrict__ count, int E) {
  int e = blockIdx.x * blockDim.x + threadIdx.x;
  if (e < E) atomicAdd(&count[te[e]], 1);
}

// 3-phase scan: scan1 (per-block inclusive + block totals), scan2 (scan totals), scan3 (apply)
__global__ void scan1_kernel(const int* __restrict__ count, int* __restrict__ incl,
                             int* __restrict__ blocksum, int T) {
  __shared__ int wsums[4];
  int tid = threadIdx.x, wave = tid >> 6, lane = tid & 63;
  int idx0 = blockIdx.x * 1024 + tid * 4;
  int c0 = 0, c1 = 0, c2 = 0, c3 = 0;
  if (idx0 + 3 < T) {
    int4 v = *(const int4*)(count + idx0);
    c0 = v.x; c1 = v.y; c2 = v.z; c3 = v.w;
  } else {
    if (idx0 < T) c0 = count[idx0];
    if (idx0 + 1 < T) c1 = count[idx0 + 1];
    if (idx0 + 2 < T) c2 = count[idx0 + 2];
  }
  int s = c0 + c1 + c2 + c3;
  int inclv = s;
#pragma unroll
  for (int off = 1; off < 64; off <<= 1) {
    int n = __shfl_up(inclv, off);
    if (lane >= off) inclv += n;
  }
  if (lane == 63) wsums[wave] = inclv;
  __syncthreads();
  int wbase = 0;
#pragma unroll
  for (int w = 0; w < 4; ++w) if (w < wave) wbase += wsums[w];
  int base = wbase + inclv - s;  // exclusive prefix for this thread's 4
  int e0 = base + c0, e1 = e0 + c1, e2 = e1 + c2, e3 = e2 + c3;
  if (idx0 < T) incl[idx0] = e0;
  if (idx0 + 1 < T) incl[idx0 + 1] = e1;
  if (idx0 + 2 < T) incl[idx0 + 2] = e2;
  if (idx0 + 3 < T) incl[idx0 + 3] = e3;
  if (tid == 255) blocksum[blockIdx.x] = wbase + inclv;
}

__global__ void scan2_kernel(const int* __restrict__ blocksum, int* __restrict__ blockbase, int nb) {
  __shared__ int wsums[4];
  int tid = threadIdx.x, wave = tid >> 6, lane = tid & 63;
  int v = (tid < nb) ? blocksum[tid] : 0;
  int inclv = v;
#pragma unroll
  for (int off = 1; off < 64; off <<= 1) {
    int n = __shfl_up(inclv, off);
    if (lane >= off) inclv += n;
  }
  if (lane == 63) wsums[wave] = inclv;
  __syncthreads();
  int wbase = 0;
#pragma unroll
  for (int w = 0; w < 4; ++w) if (w < wave) wbase += wsums[w];
  if (tid < nb) blockbase[tid] = wbase + inclv - v;  // exclusive
}

__global__ void scan3_kernel(const int* __restrict__ count, const int* __restrict__ incl,
                             const int* __restrict__ blockbase, int* __restrict__ offsets,
                             int* __restrict__ cursor, int T) {
  int idx = blockIdx.x * 1024 + threadIdx.x * 4;
  int bb = blockbase[blockIdx.x];
#pragma unroll
  for (int j = 0; j < 4; ++j) {
    int i = idx + j;
    if (i < T) {
      int o = incl[i] + bb;       // inclusive global
      offsets[i + 1] = o;
      cursor[i] = o - count[i];   // exclusive global
    }
  }
  if (blockIdx.x == 0 && threadIdx.x == 0) offsets[0] = 0;
}

__global__ void fill_kernel(const int* __restrict__ te, int* __restrict__ cursor,
                            int* __restrict__ tgt_list, int E) {
  int e = blockIdx.x * blockDim.x + threadIdx.x;
  if (e < E) {
    int s = te[e];
    int pos = atomicAdd(&cursor[s], 1);
    tgt_list[pos] = te[E + e];
  }
}

// ---------------- U = [x | geo] @ W1 (bf16 MFMA GEMM, K=288, N=256/block) ----------------
__launch_bounds__(256)
__global__ void ugemm_kernel(const float* __restrict__ x, const float* __restrict__ geo12,
                             const unsigned short* __restrict__ W1fT,
                             unsigned short* __restrict__ U, int T) {
  __shared__ alignas(16) unsigned short Al[64][40];  // pad 32->40
  int m0 = blockIdx.x * 64;
  int tid = threadIdx.x;
  int wid = tid >> 6, lane = tid & 63;
  int srow = tid >> 2, cq = tid & 3;  // staging: 4 threads/row, 8 f32 each
  int l15 = lane & 15, lhi = lane >> 4;
  int nbase = wid * 64;  // each wave owns a 64-col strip of the 256 outputs
  f32x4v acc[4][4] = {};
  const unsigned short* bp[4];
#pragma unroll
  for (int nf = 0; nf < 4; ++nf)
    bp[nf] = W1fT + (size_t)(nbase + nf * 16 + l15) * 288 + 8 * lhi;
  for (int kk = 0; kk < 9; ++kk) {
    int k0 = kk * 32;
    int t = m0 + srow;
    float f[8];
    if (kk < 8) {
      const float* sp = x + (size_t)t * 256 + k0 + cq * 8;
      float4 a = (t < T) ? *(const float4*)sp : make_float4(0, 0, 0, 0);
      float4 b = (t < T) ? *(const float4*)(sp + 4) : make_float4(0, 0, 0, 0);
      f[0] = a.x; f[1] = a.y; f[2] = a.z; f[3] = a.w;
      f[4] = b.x; f[5] = b.y; f[6] = b.z; f[7] = b.w;
    } else {
      if (cq == 0 && t < T) {
        float4 a = *(const float4*)(geo12 + (size_t)t * 12);
        float4 b = *(const float4*)(geo12 + (size_t)t * 12 + 4);
        f[0] = a.x; f[1] = a.y; f[2] = a.z; f[3] = a.w;
        f[4] = b.x; f[5] = b.y; f[6] = b.z; f[7] = b.w;
      } else if (cq == 1 && t < T) {
        float4 a = *(const float4*)(geo12 + (size_t)t * 12 + 8);
        f[0] = a.x; f[1] = a.y; f[2] = a.z; f[3] = a.w;
        f[4] = 0.f; f[5] = 0.f; f[6] = 0.f; f[7] = 0.f;
      } else {
        f[0] = f[1] = f[2] = f[3] = f[4] = f[5] = f[6] = f[7] = 0.f;
      }
    }
    short8v av;
#pragma unroll
    for (int j = 0; j < 8; ++j) av[j] = (short)f2bf(f[j]);
    *(short8v*)(&Al[srow][cq * 8]) = av;
    __syncthreads();
    short8v a[4];
#pragma unroll
    for (int mi = 0; mi < 4; ++mi)
      a[mi] = *(const short8v*)(&Al[mi * 16 + l15][8 * lhi]);
#pragma unroll
    for (int nf = 0; nf < 4; ++nf) {
      short8v b = *(const short8v*)(bp[nf] + k0);
#pragma unroll
      for (int mi = 0; mi < 4; ++mi)
        acc[mi][nf] = __builtin_amdgcn_mfma_f32_16x16x32_bf16(a[mi], b, acc[mi][nf], 0, 0, 0);
    }
    __syncthreads();
  }
#pragma unroll
  for (int mi = 0; mi < 4; ++mi) {
#pragma unroll
    for (int i = 0; i < 4; ++i) {
      int m = m0 + mi * 16 + 4 * lhi + i;
      if (m < T) {
#pragma unroll
        for (int nf = 0; nf < 4; ++nf) {
          int n = nbase + nf * 16 + l15;
          U[(size_t)m * 256 + n] = f2bf(acc[mi][nf][i]);
        }
      }
    }
  }
}

// ---------------- fused edge-gather + @W2 GEMM ----------------
__launch_bounds__(256)
__global__ void fused_kernel(const unsigned short* __restrict__ U,
                             const unsigned short* __restrict__ W2T,
                             const int* __restrict__ offsets,
                             const int* __restrict__ count,
                             const int* __restrict__ tgt_list,
                             const float* __restrict__ b1,
                             const float* __restrict__ b2,
                             float* __restrict__ out, int T) {
  __shared__ alignas(16) unsigned short hl[32][264];  // stride 528B (16B-aligned)
  int t0 = blockIdx.x * 32;
  int tid = threadIdx.x, wid = tid >> 6, lane = tid & 63;
  int c8 = (tid & 31) * 8;  // 32 lanes per row, 8 cols each
  float b1r[8];
  {
    float4 a = *(const float4*)(b1 + c8);
    float4 b = *(const float4*)(b1 + c8 + 4);
    b1r[0] = a.x; b1r[1] = a.y; b1r[2] = a.z; b1r[3] = a.w;
    b1r[4] = b.x; b1r[5] = b.y; b1r[6] = b.z; b1r[7] = b.w;
  }
#pragma unroll 1
  for (int b = 0; b < 4; ++b) {
    int r = b * 8 + (tid >> 5);
    int t = t0 + r;
    int beg = offsets[t], end = offsets[t + 1];
    short8v uvv = *(const short8v*)(U + (size_t)t * 256 + c8);
    float u[8], s[8];
#pragma unroll
    for (int j = 0; j < 8; ++j) { u[j] = bf2f((unsigned short)uvv[j]); s[j] = 0.f; }
    for (int ei = beg; ei < end; ei += 4) {
      int last = end - 1;
      int i1 = (ei + 1 <= last) ? ei + 1 : last;
      int i2 = (ei + 2 <= last) ? ei + 2 : last;
      int i3 = (ei + 3 <= last) ? ei + 3 : last;
      int g0 = tgt_list[ei], g1 = tgt_list[i1], g2 = tgt_list[i2], g3 = tgt_list[i3];
      short8v v0 = *(const short8v*)(U + (size_t)g0 * 256 + c8);
      short8v v1 = *(const short8v*)(U + (size_t)g1 * 256 + c8);
      short8v v2 = *(const short8v*)(U + (size_t)g2 * 256 + c8);
      short8v v3 = *(const short8v*)(U + (size_t)g3 * 256 + c8);
      float m1 = (ei + 1 <= last) ? 1.f : 0.f;
      float m2 = (ei + 2 <= last) ? 1.f : 0.f;
      float m3 = (ei + 3 <= last) ? 1.f : 0.f;
#pragma unroll
      for (int j = 0; j < 8; ++j) {
        float ub = u[j] + b1r[j];
        s[j] += fmaxf(ub - bf2f((unsigned short)v0[j]), 0.f)
              + m1 * fmaxf(ub - bf2f((unsigned short)v1[j]), 0.f)
              + m2 * fmaxf(ub - bf2f((unsigned short)v2[j]), 0.f)
              + m3 * fmaxf(ub - bf2f((unsigned short)v3[j]), 0.f);
      }
    }
    short8v hv;
#pragma unroll
    for (int j = 0; j < 8; ++j) hv[j] = (short)f2bf(s[j]);
    *(short8v*)(&hl[r][c8]) = hv;
  }
  __syncthreads();
  f32x4v acc[2][4] = {};
  int l15 = lane & 15, lhi = lane >> 4;
  int nbase = wid * 64;
  const unsigned short* bp[4];
  float b2r[4];
#pragma unroll
  for (int nf = 0; nf < 4; ++nf) {
    bp[nf] = W2T + (size_t)(nbase + nf * 16 + l15) * 256 + 8 * lhi;
    b2r[nf] = b2[nbase + nf * 16 + l15];
  }
  for (int kk = 0; kk < 8; ++kk) {
    int k0 = kk * 32;
    short8v a0 = *(const short8v*)(&hl[l15][k0 + 8 * lhi]);
    short8v a1 = *(const short8v*)(&hl[16 + l15][k0 + 8 * lhi]);
#pragma unroll
    for (int nf = 0; nf < 4; ++nf) {
      short8v bv = *(const short8v*)(bp[nf] + k0);
      acc[0][nf] = __builtin_amdgcn_mfma_f32_16x16x32_bf16(a0, bv, acc[0][nf], 0, 0, 0);
      acc[1][nf] = __builtin_amdgcn_mfma_f32_16x16x32_bf16(a1, bv, acc[1][nf], 0, 0, 0);
    }
  }
#pragma unroll
  for (int mi = 0; mi < 2; ++mi) {
#pragma unroll
    for (int i = 0; i < 4; ++i) {
      int m = mi * 16 + 4 * lhi + i;
      int t = t0 + m;
      if (t < T) {
        float cnt = (float)count[t];
#pragma unroll
        for (int nf = 0; nf < 4; ++nf) {
          int n = nbase + nf * 16 + l15;
          out[(size_t)t * 256 + n] = acc[mi][nf][i] + cnt * b2r[nf];
        }
      }
    }
  }
}

extern "C" void kernel_launch(void* const* d_in, const int* in_sizes, int n_in,
                              void* d_out, int out_size, void* d_ws, size_t ws_size,
                              hipStream_t stream) {
  const float* x = (const float*)d_in[0];
  const float* points = (const float*)d_in[1];
  const int* triangles = (const int*)d_in[2];
  const int* te = (const int*)d_in[3];
  const float* W1 = (const float*)d_in[4];
  const float* b1 = (const float*)d_in[5];
  const float* W2 = (const float*)d_in[6];
  const float* b2 = (const float*)d_in[7];
  float* out = (float*)d_out;
  int T = in_sizes[0] / 256;
  int E = in_sizes[3] / 2;

  char* ws = (char*)d_ws;
  size_t off = 0;
  auto alloc = [&](size_t bytes) {
    void* p = ws + off;
    off = (off + bytes + 255) & ~(size_t)255;
    return p;
  };
  unsigned short* U     = (unsigned short*)alloc((size_t)T * 256 * 2);
  float*          geo12 = (float*)alloc((size_t)T * 12 * 4);
  unsigned short* W1fT  = (unsigned short*)alloc((size_t)256 * 288 * 2);
  unsigned short* W2T   = (unsigned short*)alloc((size_t)256 * 256 * 2);
  int* count   = (int*)alloc((size_t)T * 4);
  int* offsets = (int*)alloc((size_t)(T + 1) * 4);
  int* cursor  = (int*)alloc((size_t)T * 4);
  int* tgtl    = (int*)alloc((size_t)E * 4);
  int* incl    = (int*)alloc((size_t)T * 4);
  int* bsum    = (int*)alloc(256 * 4);
  int* bbase   = (int*)alloc(256 * 4);
  if (off > ws_size) return;

  int nb1 = (T + 1023) / 1024;
  hipMemsetAsync(count, 0, (size_t)T * 4, stream);
  prep_weights<<<288, 256, 0, stream>>>(W1, W2, W1fT, W2T);
  geo_kernel<<<(T + 255) / 256, 256, 0, stream>>>(points, triangles, geo12, T);
  count_kernel<<<(E + 255) / 256, 256, 0, stream>>>(te, count, E);
  scan1_kernel<<<nb1, 256, 0, stream>>>(count, incl, bsum, T);
  scan2_kernel<<<1, 256, 0, stream>>>(bsum, bbase, nb1);
  scan3_kernel<<<nb1, 256, 0, stream>>>(count, incl, bbase, offsets, cursor, T);
  fill_kernel<<<(E + 255) / 256, 256, 0, stream>>>(te, cursor, tgtl, E);
  ugemm_kernel<<<(T + 63) / 64, 256, 0, stream>>>(x, geo12, W1fT, U, T);
  fused_kernel<<<(T + 31) / 32, 256, 0, stream>>>(U, W2T, offsets, count, tgtl, b1, b2, out, T);
}